// Round 10
// baseline (5932.118 us; speedup 1.0000x reference)
//
#include <hip/hip_runtime.h>
#include <hip/hip_bf16.h>
#include <math.h>

#define NSENT 4096
#define TT 70
#define HH 230
#define BIG 128
#define NR 53
#define GBLK 32      // sentences per gru block
#define GTHR 512     // 8 waves
#define XTOT (GBLK * 110)
#define ATHR 512

typedef float f32x4 __attribute__((ext_vector_type(4)));
typedef _Float16 f16x8 __attribute__((ext_vector_type(8)));
union U4F8 { uint4 u; f16x8 f; };
union U2H4 { uint2 u; _Float16 h[4]; };

__device__ __forceinline__ uint32_t packf16(float v) {
    _Float16 hi = (_Float16)v;
    float hif = (float)hi;
    _Float16 lo = (_Float16)(v - hif);
    union { _Float16 f; unsigned short u; } a, b;
    a.f = hi; b.f = lo;
    return ((uint32_t)a.u << 16) | (uint32_t)b.u;
}

__device__ __forceinline__ float fsig(float x) {
    x = fminf(fmaxf(x, -30.f), 30.f);
    return 1.f / (1.f + __expf(-x));
}
__device__ __forceinline__ float ftanh(float x) {
    x = fminf(fmaxf(x, -15.f), 15.f);
    float e = __expf(-2.f * x);
    return (1.f - e) / (1.f + e);
}

// ---- W frag-pack (f16): wf[((dir*12+kt)*48+nt)*64+lane] -> uint4 ----
__global__ void prep_wfrag(const float* __restrict__ w_ih_f, const float* __restrict__ w_hh_f,
                           const float* __restrict__ w_ih_b, const float* __restrict__ w_hh_b,
                           uint4* __restrict__ wf) {
    int idx = blockIdx.x * 256 + threadIdx.x;
    if (idx >= 2 * 12 * 48 * 64) return;
    int lane = idx & 63;
    int r = idx >> 6;
    int nt = r % 48; r /= 48;
    int kt = r % 12; r /= 12;
    int dir = r;
    const float* wih = dir ? w_ih_b : w_ih_f;
    const float* whh = dir ? w_hh_b : w_hh_f;
    int sec = nt >> 4;
    int j = (nt & 15) * 16 + (lane & 15);
    int q = lane >> 4;
    unsigned short hu[8];
#pragma unroll
    for (int e = 0; e < 8; ++e) {
        int k = kt * 32 + 8 * q + e;
        float v = 0.f;
        if (j < HH) {
            int g = sec * HH + j;
            if (k < HH) v = whh[g * HH + k];
            else if (k >= 256 && k < 256 + 110) v = wih[g * 110 + (k - 256)];
        }
        union { _Float16 f; unsigned short u; } a;
        a.f = (_Float16)v;
        hu[e] = a.u;
    }
    uint4 H;
    H.x = (uint32_t)hu[0] | ((uint32_t)hu[1] << 16);
    H.y = (uint32_t)hu[2] | ((uint32_t)hu[3] << 16);
    H.z = (uint32_t)hu[4] | ((uint32_t)hu[5] << 16);
    H.w = (uint32_t)hu[6] | ((uint32_t)hu[7] << 16);
    wf[idx] = H;
}

__device__ __forceinline__ void unpackA(uint4 p0, uint4 p1, f16x8& hi, f16x8& lo) {
    U4F8 h, l;
    h.u.x = (p0.x >> 16) | (p0.y & 0xffff0000u);
    h.u.y = (p0.z >> 16) | (p0.w & 0xffff0000u);
    h.u.z = (p1.x >> 16) | (p1.y & 0xffff0000u);
    h.u.w = (p1.z >> 16) | (p1.w & 0xffff0000u);
    l.u.x = (p0.x & 0xffffu) | (p0.y << 16);
    l.u.y = (p0.z & 0xffffu) | (p0.w << 16);
    l.u.z = (p1.x & 0xffffu) | (p1.y << 16);
    l.u.w = (p1.z & 0xffffu) | (p1.w << 16);
    hi = h.f; lo = l.f;
}

// ---- fused GRU, one direction per block, XCD dir-pinned, (A f16-pair)x(B f16) ----
extern __shared__ uint32_t lds[];   // hA: 32*256 u32 (32KB), xA: 32*128 u32 (16KB)

__global__ __launch_bounds__(GTHR, 2)
void gru_kernel(const int* __restrict__ sentence, const int* __restrict__ pos1, const int* __restrict__ pos2,
                const uint4* __restrict__ wf,
                const float* __restrict__ word_emb, const float* __restrict__ p1e, const float* __restrict__ p2e,
                const float* __restrict__ b_ih_f, const float* __restrict__ b_hh_f,
                const float* __restrict__ b_ih_b, const float* __restrict__ b_hh_b,
                _Float16* __restrict__ tupF, _Float16* __restrict__ tupB) {
    uint32_t* hA = lds;              // [row][k] packed, uint4-slot XOR swizzle by (row&7)
    uint32_t* xA = lds + GBLK * 256;
    const uint4* hA4 = (const uint4*)hA;
    const uint4* xA4 = (const uint4*)xA;

    const int tid = threadIdx.x;
    const int lane = tid & 63;
    const int wv = tid >> 6;
    const int q = lane >> 4;
    const int lr = lane & 15;
    // XCD pinning: blockIdx round-robins over 8 XCDs; XCD 0-3 -> dir0, 4-7 -> dir1.
    const int b = blockIdx.x;
    const int xcd = b & 7;
    const int dir = (xcd >= 4) ? 1 : 0;
    const int chunk = (b >> 3) * 4 + (xcd & 3);   // 0..127 per dir
    const int r0 = chunk * GBLK;
    uint32_t* tupU = (uint32_t*)(dir ? tupB : tupF);   // 115 u32 per (n,t), f16 pairs

    for (int i = tid; i < GBLK * (256 + 128); i += GTHR) lds[i] = 0;

    auto fetch_x = [&](int u, int t) -> float {
        int row = u / 110;
        int i = u - row * 110;
        int nn = r0 + row;
        if (i < 100)      return __builtin_nontemporal_load(&word_emb[(size_t)sentence[nn * TT + t] * 100 + i]);
        else if (i < 105) return __builtin_nontemporal_load(&p1e[pos1[nn * TT + t] * 5 + (i - 100)]);
        else              return __builtin_nontemporal_load(&p2e[pos2[nn * TT + t] * 5 + (i - 105)]);
    };
    auto xslot = [&](int u) -> int {
        int row = u / 110;
        int i = u - row * 110;
        return row * 128 + ((((i >> 2) ^ (row & 7)) << 2) | (i & 3));
    };

    __syncthreads();
    {   // initial x gather (direct to LDS)
        int t0 = dir ? TT - 1 : 0;
        for (int u = tid; u < XTOT; u += GTHR) xA[xslot(u)] = packf16(fetch_x(u, t0));
    }
    __syncthreads();

    const float* bih = dir ? b_ih_b : b_ih_f;
    const float* bhh = dir ? b_hh_b : b_hh_f;
    float bR[2], bZ[2], bHn[2], bIn[2];
    int jc[2];
#pragma unroll
    for (int rt = 0; rt < 2; ++rt) {
        int j = 32 * wv + 16 * rt + lr;
        jc[rt] = j;
        bool v = j < HH;
        bR[rt]  = v ? bih[j] + bhh[j] : 0.f;
        bZ[rt]  = v ? bih[HH + j] + bhh[HH + j] : 0.f;
        bIn[rt] = v ? bih[2 * HH + j] : 0.f;
        bHn[rt] = v ? bhh[2 * HH + j] : 0.f;
    }
    float hreg[16];
#pragma unroll
    for (int i = 0; i < 16; ++i) hreg[i] = 0.f;

    const int r7 = lr & 7;
    const size_t wdirbase = (size_t)dir * 12 * 48;

    // continuous cross-step prefetch ring (weights are step-invariant):
    // consumption at global iter g=(s*36+idx) uses slot g&7 = (s*4+idx)&7;
    // prefetch widx=(idx+7)%36 into slot (g+7)&7 every iteration, unconditionally.
    uint4 BH[8][2];
    auto loadB = [&](int slot, int widx) {
        const int kt = widx / 3, pp = widx - 3 * kt;
        const int nt = 2 * wv + ((pp == 0) ? 0 : (pp == 1) ? 16 : 32);
        const uint4* p = wf + (wdirbase + (size_t)kt * 48 + nt) * 64 + lane;
        BH[slot][0] = p[0];
        BH[slot][1] = p[64];
    };
#pragma unroll
    for (int g = 0; g < 7; ++g) loadB(g & 7, g);   // prologue: fill ring

    for (int s = 0; s < TT; ++s) {
        const int t = dir ? (TT - 1 - s) : s;
        const int sb0 = (s * 4) & 7;               // ring phase for this step
        // stage next-step x into regs (latency hidden under GEMM)
        float gx[7];
        if (s < TT - 1) {
            const int tn = dir ? t - 1 : t + 1;
#pragma unroll
            for (int c = 0; c < 7; ++c) {
                int u = tid + c * GTHR;
                if (u < XTOT) gx[c] = fetch_x(u, tn);
            }
        }

        f32x4 acc[2][8];
#pragma unroll
        for (int m = 0; m < 2; ++m)
#pragma unroll
            for (int c = 0; c < 8; ++c) acc[m][c] = (f32x4){0.f, 0.f, 0.f, 0.f};

        f16x8 Ahi[2], Alo[2];
#pragma unroll
        for (int idx = 0; idx < 36; ++idx) {
            const int kt = idx / 3, pp = idx - 3 * kt;
            if (pp == 0) {
#pragma unroll
                for (int m = 0; m < 2; ++m) {
                    int row = m * 16 + lr;
                    uint4 p0, p1;
                    if (kt < 8) {
                        int bb = kt * 8 + 2 * q;
                        p0 = hA4[row * 64 + ((bb)     ^ r7)];
                        p1 = hA4[row * 64 + ((bb + 1) ^ r7)];
                    } else {
                        int bb = (kt - 8) * 8 + 2 * q;
                        p0 = xA4[row * 32 + ((bb)     ^ r7)];
                        p1 = xA4[row * 32 + ((bb + 1) ^ r7)];
                    }
                    unpackA(p0, p1, Ahi[m], Alo[m]);
                }
            }
            loadB((sb0 + idx + 7) & 7, (idx + 7) % 36);   // cross-step continuous prefetch
            const int sb = (sb0 + idx) & 7;
            // term-outer: dependent MFMAs on same acc are 4 apart
#pragma unroll
            for (int term = 0; term < 2; ++term)
#pragma unroll
                for (int u = 0; u < 2; ++u) {
                    const int slot = (pp < 2) ? pp * 2 + u : (kt < 8 ? 4 + u : 6 + u);
                    U4F8 B; B.u = BH[sb][u];
#pragma unroll
                    for (int m = 0; m < 2; ++m) {
                        f16x8 A = term ? Alo[m] : Ahi[m];
                        acc[m][slot] = __builtin_amdgcn_mfma_f32_16x16x32_f16(A, B.f, acc[m][slot], 0, 0, 0);
                    }
                }
        }
        __syncthreads();   // all hA/xA reads done

        // nonlinearity + h update -> LDS only (C layout: col=lane&15, row=(lane>>4)*4+reg)
#pragma unroll
        for (int m = 0; m < 2; ++m)
#pragma unroll
            for (int rt = 0; rt < 2; ++rt)
#pragma unroll
                for (int rg = 0; rg < 4; ++rg) {
                    int row = m * 16 + q * 4 + rg;
                    float vr = fsig(acc[m][rt][rg] + bR[rt]);
                    float vz = fsig(acc[m][2 + rt][rg] + bZ[rt]);
                    float gn = acc[m][4 + rt][rg] + bHn[rt];
                    float xn = acc[m][6 + rt][rg] + bIn[rt];
                    float vn = ftanh(xn + vr * gn);
                    int hi_ = m * 8 + rt * 4 + rg;
                    float h = (1.f - vz) * vn + vz * hreg[hi_];
                    hreg[hi_] = h;
                    int j = jc[rt];
                    hA[row * 256 + ((((j >> 2) ^ (row & 7)) << 2) | (j & 3))] = packf16(h);
                }
        // commit staged x for next step
        if (s < TT - 1) {
#pragma unroll
            for (int c = 0; c < 7; ++c) {
                int u = tid + c * GTHR;
                if (u < XTOT) xA[xslot(u)] = packf16(gx[c]);
            }
        }
        __syncthreads();

        // coalesced tup writeback from hA (f16 value = top half of packed u32)
        for (int u = tid; u < GBLK * 115; u += GTHR) {
            int row = u / 115, c = u - row * 115;
            int bi = row * 256 + ((((c >> 1) ^ (row & 7)) << 2) | (2 * (c & 1)));
            uint32_t p0 = hA[bi];
            uint32_t p1 = hA[bi + 1];
            uint32_t o = (p0 >> 16) | (p1 & 0xffff0000u);
            __builtin_nontemporal_store(o, &tupU[((size_t)(r0 + row) * TT + t) * 115 + c]);
        }
        // next GEMM only READS hA/xA; writeback reads complete before each
        // thread's next post-GEMM barrier.
    }
}

// -------- word attention + sentence repr + bag scalar e (reads hf+hb f16) --------
__global__ __launch_bounds__(ATHR)
void attn_kernel(const _Float16* __restrict__ tupF, const _Float16* __restrict__ tupB,
                 const float* __restrict__ aw,
                 const float* __restrict__ sen_a, const float* __restrict__ sen_r,
                 float* __restrict__ sen_repre, float* __restrict__ e_out) {
    __shared__ float tb[TT * HH];
    __shared__ float sc[TT + 2];
    const int n = blockIdx.x, tid = threadIdx.x;
    const uint2* pF = (const uint2*)(tupF + (size_t)n * TT * HH);
    const uint2* pB = (const uint2*)(tupB + (size_t)n * TT * HH);
    for (int u = tid; u < TT * HH / 4; u += ATHR) {
        U2H4 a, b;
        a.u = pF[u]; b.u = pB[u];
#pragma unroll
        for (int e2 = 0; e2 < 4; ++e2)
            tb[4 * u + e2] = (float)a.h[e2] + (float)b.h[e2];
    }
    __syncthreads();
    {   // scores: one 4-lane group per t
        int tg = tid >> 2, sub = tid & 3;
        if (tg < TT) {
            float s = 0.f;
            for (int k = sub; k < HH; k += 4) s += ftanh(tb[tg * HH + k]) * aw[k];
            s += __shfl_xor(s, 1);
            s += __shfl_xor(s, 2);
            if (sub == 0) sc[tg] = s;
        }
    }
    __syncthreads();
    if (tid == 0) {
        float m = sc[0];
        for (int t2 = 1; t2 < TT; ++t2) m = fmaxf(m, sc[t2]);
        float den = 0.f;
        for (int t2 = 0; t2 < TT; ++t2) { float ex = __expf(sc[t2] - m); sc[t2] = ex; den += ex; }
        float inv = 1.f / den;
        for (int t2 = 0; t2 < TT; ++t2) sc[t2] *= inv;
    }
    __syncthreads();
    float contrib = 0.f;
    if (tid < HH) {
        float ar = 0.f;
        for (int t2 = 0; t2 < TT; ++t2) ar += sc[t2] * tb[t2 * HH + tid];
        float sr = tanhf(ar);
        sen_repre[(size_t)n * HH + tid] = sr;
        contrib = sr * sen_a[tid] * sen_r[tid];
    }
    __syncthreads();           // tb reads done; reuse tb[0..255] as reduce scratch
    if (tid < 256) tb[tid] = (tid < HH) ? contrib : 0.f;
    __syncthreads();
#pragma unroll
    for (int off = 128; off > 0; off >>= 1) {
        if (tid < off) tb[tid] += tb[tid + off];
        __syncthreads();
    }
    if (tid == 0) e_out[n] = tb[0];
}

// -------- per-bag attention, logits, prob, bce, acc --------
__global__ __launch_bounds__(256)
void bag_kernel(const int* __restrict__ total_shape, const float* __restrict__ e,
                const float* __restrict__ senr, const float* __restrict__ rel,
                const float* __restrict__ sen_d, const float* __restrict__ y,
                float* __restrict__ out, float* __restrict__ lossp) {
    __shared__ float ew[512];
    __shared__ float ss[232];
    __shared__ float lg[56];
    const int b = blockIdx.x, tid = threadIdx.x;
    const int s0 = total_shape[b], s1 = total_shape[b + 1];
    const int cnt = s1 - s0;
    for (int i = tid; i < cnt; i += 256) ew[i] = e[s0 + i];
    __syncthreads();
    if (tid == 0) {
        float m = ew[0];
        for (int i = 1; i < cnt; ++i) m = fmaxf(m, ew[i]);
        float den = 0.f;
        for (int i = 0; i < cnt; ++i) { float ex = expf(ew[i] - m); ew[i] = ex; den += ex; }
        float inv = 1.f / den;
        for (int i = 0; i < cnt; ++i) ew[i] *= inv;
    }
    __syncthreads();
    if (tid < HH) {
        float sacc = 0.f;
        for (int i = 0; i < cnt; ++i) sacc += ew[i] * senr[(size_t)(s0 + i) * HH + tid];
        ss[tid] = sacc;
    }
    __syncthreads();
    if (tid < NR) {
        float sacc = sen_d[tid];
        for (int j = 0; j < HH; ++j) sacc += ss[j] * rel[tid * HH + j];
        lg[tid] = sacc;
    }
    __syncthreads();
    if (tid == 0) {
        float m = lg[0]; int pm = 0;
        for (int k = 1; k < NR; ++k) if (lg[k] > m) { m = lg[k]; pm = k; }
        float den = 0.f;
        for (int k = 0; k < NR; ++k) den += expf(lg[k] - m);
        float inv = 1.f / den;
        float bces = 0.f;
        float ym = y[b * NR]; int yarg = 0;
        for (int k = 0; k < NR; ++k) {
            float p = expf(lg[k] - m) * inv;
            out[1 + BIG + b * NR + k] = p;
            float yy = y[b * NR + k];
            if (yy > ym) { ym = yy; yarg = k; }
            float l = lg[k];
            float sp_pos = fmaxf(l, 0.f) + log1pf(expf(-fabsf(l)));
            float sp_neg = sp_pos - l;
            bces += yy * sp_neg + (1.f - yy) * sp_pos;
        }
        lossp[b] = bces * (1.f / (float)NR);
        out[1 + b] = (pm == yarg) ? 1.f : 0.f;
    }
}

__global__ void loss_sum(const float* __restrict__ lossp, float* __restrict__ out) {
    if (threadIdx.x == 0) {
        float sacc = 0.f;
        for (int b2 = 0; b2 < BIG; ++b2) sacc += lossp[b2];
        out[0] = sacc;
    }
}

extern "C" void kernel_launch(void* const* d_in, const int* in_sizes, int n_in,
                              void* d_out, int out_size, void* d_ws, size_t ws_size,
                              hipStream_t stream) {
    const int*   sentence = (const int*)d_in[0];
    const int*   pos1     = (const int*)d_in[1];
    const int*   pos2     = (const int*)d_in[2];
    const int*   tshape   = (const int*)d_in[3];
    const float* y_batch  = (const float*)d_in[4];
    const float* word_emb = (const float*)d_in[5];
    const float* p1e      = (const float*)d_in[6];
    const float* p2e      = (const float*)d_in[7];
    const float* w_ih_f   = (const float*)d_in[8];
    const float* w_hh_f   = (const float*)d_in[9];
    const float* b_ih_f   = (const float*)d_in[10];
    const float* b_hh_f   = (const float*)d_in[11];
    const float* w_ih_b   = (const float*)d_in[12];
    const float* w_hh_b   = (const float*)d_in[13];
    const float* b_ih_b   = (const float*)d_in[14];
    const float* b_hh_b   = (const float*)d_in[15];
    const float* att_w    = (const float*)d_in[16];
    const float* sen_a    = (const float*)d_in[17];
    const float* sen_r    = (const float*)d_in[18];
    const float* rel      = (const float*)d_in[19];
    const float* sen_d    = (const float*)d_in[20];
    float* out = (float*)d_out;

    // ws layout: tupF f16 | tupB f16 | senr f32 (wf aliased on top) | e | lossp
    const size_t TUP_E  = (size_t)NSENT * TT * HH;
    const size_t SENR_F = (size_t)NSENT * HH;
    _Float16* tupF = (_Float16*)d_ws;
    _Float16* tupB = tupF + TUP_E;
    float* senr  = (float*)(tupB + TUP_E);
    float* e     = senr + SENR_F;
    float* lossp = e + NSENT;
    uint4* wf    = (uint4*)senr;   // 1.18 MB inside senr's 3.77 MB; dead before attn writes senr

    prep_wfrag<<<288, 256, 0, stream>>>(w_ih_f, w_hh_f, w_ih_b, w_hh_b, wf);
    gru_kernel<<<(NSENT / GBLK) * 2, GTHR, GBLK * (256 + 128) * 4, stream>>>(
        sentence, pos1, pos2, wf, word_emb, p1e, p2e,
        b_ih_f, b_hh_f, b_ih_b, b_hh_b, tupF, tupB);
    attn_kernel<<<NSENT, ATHR, 0, stream>>>(tupF, tupB, att_w, sen_a, sen_r, senr, e);
    bag_kernel<<<BIG, 256, 0, stream>>>(tshape, e, senr, rel, sen_d, y_batch, out, lossp);
    loss_sum<<<1, 64, 0, stream>>>(lossp, out);
}

// Round 11
// 2618.347 us; speedup vs baseline: 2.2656x; 2.2656x over previous
//
#include <hip/hip_runtime.h>
#include <hip/hip_bf16.h>
#include <math.h>
#include <type_traits>

#define NSENT 4096
#define TT 70
#define HH 230
#define BIG 128
#define NR 53
#define GBLK 32      // sentences per gru block
#define GTHR 512     // 8 waves
#define XTOT (GBLK * 110)
#define ATHR 512

typedef float f32x4 __attribute__((ext_vector_type(4)));
typedef _Float16 f16x8 __attribute__((ext_vector_type(8)));
union U4F8 { uint4 u; f16x8 f; };
union U2H4 { uint2 u; _Float16 h[4]; };

__device__ __forceinline__ uint32_t packf16(float v) {
    _Float16 hi = (_Float16)v;
    float hif = (float)hi;
    _Float16 lo = (_Float16)(v - hif);
    union { _Float16 f; unsigned short u; } a, b;
    a.f = hi; b.f = lo;
    return ((uint32_t)a.u << 16) | (uint32_t)b.u;
}

__device__ __forceinline__ float fsig(float x) {
    x = fminf(fmaxf(x, -30.f), 30.f);
    return 1.f / (1.f + __expf(-x));
}
__device__ __forceinline__ float ftanh(float x) {
    x = fminf(fmaxf(x, -15.f), 15.f);
    float e = __expf(-2.f * x);
    return (1.f - e) / (1.f + e);
}

// ---- W frag-pack (f16): wf[((dir*12+kt)*48+nt)*64+lane] -> uint4 ----
__global__ void prep_wfrag(const float* __restrict__ w_ih_f, const float* __restrict__ w_hh_f,
                           const float* __restrict__ w_ih_b, const float* __restrict__ w_hh_b,
                           uint4* __restrict__ wf) {
    int idx = blockIdx.x * 256 + threadIdx.x;
    if (idx >= 2 * 12 * 48 * 64) return;
    int lane = idx & 63;
    int r = idx >> 6;
    int nt = r % 48; r /= 48;
    int kt = r % 12; r /= 12;
    int dir = r;
    const float* wih = dir ? w_ih_b : w_ih_f;
    const float* whh = dir ? w_hh_b : w_hh_f;
    int sec = nt >> 4;
    int j = (nt & 15) * 16 + (lane & 15);
    int q = lane >> 4;
    unsigned short hu[8];
#pragma unroll
    for (int e = 0; e < 8; ++e) {
        int k = kt * 32 + 8 * q + e;
        float v = 0.f;
        if (j < HH) {
            int g = sec * HH + j;
            if (k < HH) v = whh[g * HH + k];
            else if (k >= 256 && k < 256 + 110) v = wih[g * 110 + (k - 256)];
        }
        union { _Float16 f; unsigned short u; } a;
        a.f = (_Float16)v;
        hu[e] = a.u;
    }
    uint4 H;
    H.x = (uint32_t)hu[0] | ((uint32_t)hu[1] << 16);
    H.y = (uint32_t)hu[2] | ((uint32_t)hu[3] << 16);
    H.z = (uint32_t)hu[4] | ((uint32_t)hu[5] << 16);
    H.w = (uint32_t)hu[6] | ((uint32_t)hu[7] << 16);
    wf[idx] = H;
}

__device__ __forceinline__ void unpackA(uint4 p0, uint4 p1, f16x8& hi, f16x8& lo) {
    U4F8 h, l;
    h.u.x = (p0.x >> 16) | (p0.y & 0xffff0000u);
    h.u.y = (p0.z >> 16) | (p0.w & 0xffff0000u);
    h.u.z = (p1.x >> 16) | (p1.y & 0xffff0000u);
    h.u.w = (p1.z >> 16) | (p1.w & 0xffff0000u);
    l.u.x = (p0.x & 0xffffu) | (p0.y << 16);
    l.u.y = (p0.z & 0xffffu) | (p0.w << 16);
    l.u.z = (p1.x & 0xffffu) | (p1.y << 16);
    l.u.w = (p1.z & 0xffffu) | (p1.w << 16);
    hi = h.f; lo = l.f;
}

// ---- fused GRU, one dir per block, XCD dir-pinned, (A f16-pair)x(B f16) MFMA ----
extern __shared__ uint32_t lds[];   // hA: 32*256 u32 (32KB), xA: 32*128 u32 (16KB)

__global__ __launch_bounds__(GTHR, 2)
void gru_kernel(const int* __restrict__ sentence, const int* __restrict__ pos1, const int* __restrict__ pos2,
                const uint4* __restrict__ wf,
                const float* __restrict__ word_emb, const float* __restrict__ p1e, const float* __restrict__ p2e,
                const float* __restrict__ b_ih_f, const float* __restrict__ b_hh_f,
                const float* __restrict__ b_ih_b, const float* __restrict__ b_hh_b,
                _Float16* __restrict__ tupF, _Float16* __restrict__ tupB) {
    uint32_t* hA = lds;              // [row][k] packed, uint4-slot XOR swizzle by (row&7)
    uint32_t* xA = lds + GBLK * 256;
    const uint4* hA4 = (const uint4*)hA;
    const uint4* xA4 = (const uint4*)xA;

    const int tid = threadIdx.x;
    const int lane = tid & 63;
    const int wv = tid >> 6;
    const int q = lane >> 4;
    const int lr = lane & 15;
    // XCD pinning: blockIdx round-robins over 8 XCDs; XCD 0-3 -> dir0, 4-7 -> dir1.
    const int b = blockIdx.x;
    const int xcd = b & 7;
    const int dir = (xcd >= 4) ? 1 : 0;
    const int chunk = (b >> 3) * 4 + (xcd & 3);   // 0..127 per dir
    const int r0 = chunk * GBLK;
    uint32_t* tupU = (uint32_t*)(dir ? tupB : tupF);   // 115 u32 per (n,t), f16 pairs

    for (int i = tid; i < GBLK * (256 + 128); i += GTHR) lds[i] = 0;

    auto fetch_x = [&](int u, int t) -> float {
        int row = u / 110;
        int i = u - row * 110;
        int nn = r0 + row;
        if (i < 100)      return __builtin_nontemporal_load(&word_emb[(size_t)sentence[nn * TT + t] * 100 + i]);
        else if (i < 105) return __builtin_nontemporal_load(&p1e[pos1[nn * TT + t] * 5 + (i - 100)]);
        else              return __builtin_nontemporal_load(&p2e[pos2[nn * TT + t] * 5 + (i - 105)]);
    };
    auto xslot = [&](int u) -> int {
        int row = u / 110;
        int i = u - row * 110;
        return row * 128 + ((((i >> 2) ^ (row & 7)) << 2) | (i & 3));
    };

    __syncthreads();
    {   // initial x gather (direct to LDS)
        int t0 = dir ? TT - 1 : 0;
        for (int u = tid; u < XTOT; u += GTHR) xA[xslot(u)] = packf16(fetch_x(u, t0));
    }
    __syncthreads();

    const float* bih = dir ? b_ih_b : b_ih_f;
    const float* bhh = dir ? b_hh_b : b_hh_f;
    float bR[2], bZ[2], bHn[2], bIn[2];
    int jc[2];
#pragma unroll
    for (int rt = 0; rt < 2; ++rt) {
        int j = 32 * wv + 16 * rt + lr;
        jc[rt] = j;
        bool v = j < HH;
        bR[rt]  = v ? bih[j] + bhh[j] : 0.f;
        bZ[rt]  = v ? bih[HH + j] + bhh[HH + j] : 0.f;
        bIn[rt] = v ? bih[2 * HH + j] : 0.f;
        bHn[rt] = v ? bhh[2 * HH + j] : 0.f;
    }
    float hreg[16];
#pragma unroll
    for (int i = 0; i < 16; ++i) hreg[i] = 0.f;

    const int r7 = lr & 7;
    const size_t wdirbase = (size_t)dir * 12 * 48;

    // continuous cross-step prefetch ring; ALL slot indices compile-time
    // (36 ≡ 4 mod 8 -> phase alternates 0/4 with step parity; body templated on it).
    uint4 BH[8][2];
    auto loadB = [&](int slot, int widx) {   // slot/widx must be compile-time constants
        const int kt = widx / 3, pp = widx - 3 * kt;
        const int nt = 2 * wv + ((pp == 0) ? 0 : (pp == 1) ? 16 : 32);
        const uint4* p = wf + (wdirbase + (size_t)kt * 48 + nt) * 64 + lane;
        BH[slot][0] = p[0];
        BH[slot][1] = p[64];
    };
#pragma unroll
    for (int g = 0; g < 7; ++g) loadB(g & 7, g);   // prologue: fill ring

    auto run_step = [&](auto sb0c, int s, int t) {
        constexpr int SB0 = decltype(sb0c)::value;
        // stage next-step x into regs (latency hidden under GEMM)
        float gx[7];
        if (s < TT - 1) {
            const int tn = dir ? t - 1 : t + 1;
#pragma unroll
            for (int c = 0; c < 7; ++c) {
                int u = tid + c * GTHR;
                if (u < XTOT) gx[c] = fetch_x(u, tn);
            }
        }

        f32x4 acc[2][8];
#pragma unroll
        for (int m = 0; m < 2; ++m)
#pragma unroll
            for (int c = 0; c < 8; ++c) acc[m][c] = (f32x4){0.f, 0.f, 0.f, 0.f};

        f16x8 Ahi[2], Alo[2];
#pragma unroll
        for (int idx = 0; idx < 36; ++idx) {
            const int kt = idx / 3, pp = idx - 3 * kt;
            if (pp == 0) {
#pragma unroll
                for (int m = 0; m < 2; ++m) {
                    int row = m * 16 + lr;
                    uint4 p0, p1;
                    if (kt < 8) {
                        int bb = kt * 8 + 2 * q;
                        p0 = hA4[row * 64 + ((bb)     ^ r7)];
                        p1 = hA4[row * 64 + ((bb + 1) ^ r7)];
                    } else {
                        int bb = (kt - 8) * 8 + 2 * q;
                        p0 = xA4[row * 32 + ((bb)     ^ r7)];
                        p1 = xA4[row * 32 + ((bb + 1) ^ r7)];
                    }
                    unpackA(p0, p1, Ahi[m], Alo[m]);
                }
            }
            loadB((SB0 + idx + 7) & 7, (idx + 7) % 36);   // compile-time slot
            const int sb = (SB0 + idx) & 7;               // compile-time slot
            // term-outer: dependent MFMAs on same acc are 4 apart
#pragma unroll
            for (int term = 0; term < 2; ++term)
#pragma unroll
                for (int u = 0; u < 2; ++u) {
                    const int slot = (pp < 2) ? pp * 2 + u : (kt < 8 ? 4 + u : 6 + u);
                    U4F8 B; B.u = BH[sb][u];
#pragma unroll
                    for (int m = 0; m < 2; ++m) {
                        f16x8 A = term ? Alo[m] : Ahi[m];
                        acc[m][slot] = __builtin_amdgcn_mfma_f32_16x16x32_f16(A, B.f, acc[m][slot], 0, 0, 0);
                    }
                }
        }
        __syncthreads();   // all hA/xA reads done

        // nonlinearity + h update -> LDS only (C layout: col=lane&15, row=(lane>>4)*4+reg)
#pragma unroll
        for (int m = 0; m < 2; ++m)
#pragma unroll
            for (int rt = 0; rt < 2; ++rt)
#pragma unroll
                for (int rg = 0; rg < 4; ++rg) {
                    int row = m * 16 + q * 4 + rg;
                    float vr = fsig(acc[m][rt][rg] + bR[rt]);
                    float vz = fsig(acc[m][2 + rt][rg] + bZ[rt]);
                    float gn = acc[m][4 + rt][rg] + bHn[rt];
                    float xn = acc[m][6 + rt][rg] + bIn[rt];
                    float vn = ftanh(xn + vr * gn);
                    int hi_ = m * 8 + rt * 4 + rg;
                    float h = (1.f - vz) * vn + vz * hreg[hi_];
                    hreg[hi_] = h;
                    int j = jc[rt];
                    hA[row * 256 + ((((j >> 2) ^ (row & 7)) << 2) | (j & 3))] = packf16(h);
                }
        // commit staged x for next step
        if (s < TT - 1) {
#pragma unroll
            for (int c = 0; c < 7; ++c) {
                int u = tid + c * GTHR;
                if (u < XTOT) xA[xslot(u)] = packf16(gx[c]);
            }
        }
        __syncthreads();

        // coalesced tup writeback from hA (f16 value = top half of packed u32)
        for (int u = tid; u < GBLK * 115; u += GTHR) {
            int row = u / 115, c = u - row * 115;
            int bi = row * 256 + ((((c >> 1) ^ (row & 7)) << 2) | (2 * (c & 1)));
            uint32_t p0 = hA[bi];
            uint32_t p1 = hA[bi + 1];
            uint32_t o = (p0 >> 16) | (p1 & 0xffff0000u);
            __builtin_nontemporal_store(o, &tupU[((size_t)(r0 + row) * TT + t) * 115 + c]);
        }
        // next GEMM only READS hA/xA; writeback reads complete before each
        // thread's next post-GEMM barrier.
    };

    for (int s = 0; s < TT; ++s) {
        const int t = dir ? (TT - 1 - s) : s;
        if (s & 1) run_step(std::integral_constant<int, 4>{}, s, t);
        else       run_step(std::integral_constant<int, 0>{}, s, t);
    }
}

// -------- word attention + sentence repr + bag scalar e (reads hf+hb f16) --------
__global__ __launch_bounds__(ATHR)
void attn_kernel(const _Float16* __restrict__ tupF, const _Float16* __restrict__ tupB,
                 const float* __restrict__ aw,
                 const float* __restrict__ sen_a, const float* __restrict__ sen_r,
                 float* __restrict__ sen_repre, float* __restrict__ e_out) {
    __shared__ float tb[TT * HH];
    __shared__ float sc[TT + 2];
    const int n = blockIdx.x, tid = threadIdx.x;
    const uint2* pF = (const uint2*)(tupF + (size_t)n * TT * HH);
    const uint2* pB = (const uint2*)(tupB + (size_t)n * TT * HH);
    for (int u = tid; u < TT * HH / 4; u += ATHR) {
        U2H4 a, b;
        a.u = pF[u]; b.u = pB[u];
#pragma unroll
        for (int e2 = 0; e2 < 4; ++e2)
            tb[4 * u + e2] = (float)a.h[e2] + (float)b.h[e2];
    }
    __syncthreads();
    {   // scores: one 4-lane group per t
        int tg = tid >> 2, sub = tid & 3;
        if (tg < TT) {
            float s = 0.f;
            for (int k = sub; k < HH; k += 4) s += ftanh(tb[tg * HH + k]) * aw[k];
            s += __shfl_xor(s, 1);
            s += __shfl_xor(s, 2);
            if (sub == 0) sc[tg] = s;
        }
    }
    __syncthreads();
    if (tid == 0) {
        float m = sc[0];
        for (int t2 = 1; t2 < TT; ++t2) m = fmaxf(m, sc[t2]);
        float den = 0.f;
        for (int t2 = 0; t2 < TT; ++t2) { float ex = __expf(sc[t2] - m); sc[t2] = ex; den += ex; }
        float inv = 1.f / den;
        for (int t2 = 0; t2 < TT; ++t2) sc[t2] *= inv;
    }
    __syncthreads();
    float contrib = 0.f;
    if (tid < HH) {
        float ar = 0.f;
        for (int t2 = 0; t2 < TT; ++t2) ar += sc[t2] * tb[t2 * HH + tid];
        float sr = tanhf(ar);
        sen_repre[(size_t)n * HH + tid] = sr;
        contrib = sr * sen_a[tid] * sen_r[tid];
    }
    __syncthreads();           // tb reads done; reuse tb[0..255] as reduce scratch
    if (tid < 256) tb[tid] = (tid < HH) ? contrib : 0.f;
    __syncthreads();
#pragma unroll
    for (int off = 128; off > 0; off >>= 1) {
        if (tid < off) tb[tid] += tb[tid + off];
        __syncthreads();
    }
    if (tid == 0) e_out[n] = tb[0];
}

// -------- per-bag attention, logits, prob, bce, acc --------
__global__ __launch_bounds__(256)
void bag_kernel(const int* __restrict__ total_shape, const float* __restrict__ e,
                const float* __restrict__ senr, const float* __restrict__ rel,
                const float* __restrict__ sen_d, const float* __restrict__ y,
                float* __restrict__ out, float* __restrict__ lossp) {
    __shared__ float ew[512];
    __shared__ float ss[232];
    __shared__ float lg[56];
    const int b = blockIdx.x, tid = threadIdx.x;
    const int s0 = total_shape[b], s1 = total_shape[b + 1];
    const int cnt = s1 - s0;
    for (int i = tid; i < cnt; i += 256) ew[i] = e[s0 + i];
    __syncthreads();
    if (tid == 0) {
        float m = ew[0];
        for (int i = 1; i < cnt; ++i) m = fmaxf(m, ew[i]);
        float den = 0.f;
        for (int i = 0; i < cnt; ++i) { float ex = expf(ew[i] - m); ew[i] = ex; den += ex; }
        float inv = 1.f / den;
        for (int i = 0; i < cnt; ++i) ew[i] *= inv;
    }
    __syncthreads();
    if (tid < HH) {
        float sacc = 0.f;
        for (int i = 0; i < cnt; ++i) sacc += ew[i] * senr[(size_t)(s0 + i) * HH + tid];
        ss[tid] = sacc;
    }
    __syncthreads();
    if (tid < NR) {
        float sacc = sen_d[tid];
        for (int j = 0; j < HH; ++j) sacc += ss[j] * rel[tid * HH + j];
        lg[tid] = sacc;
    }
    __syncthreads();
    if (tid == 0) {
        float m = lg[0]; int pm = 0;
        for (int k = 1; k < NR; ++k) if (lg[k] > m) { m = lg[k]; pm = k; }
        float den = 0.f;
        for (int k = 0; k < NR; ++k) den += expf(lg[k] - m);
        float inv = 1.f / den;
        float bces = 0.f;
        float ym = y[b * NR]; int yarg = 0;
        for (int k = 0; k < NR; ++k) {
            float p = expf(lg[k] - m) * inv;
            out[1 + BIG + b * NR + k] = p;
            float yy = y[b * NR + k];
            if (yy > ym) { ym = yy; yarg = k; }
            float l = lg[k];
            float sp_pos = fmaxf(l, 0.f) + log1pf(expf(-fabsf(l)));
            float sp_neg = sp_pos - l;
            bces += yy * sp_neg + (1.f - yy) * sp_pos;
        }
        lossp[b] = bces * (1.f / (float)NR);
        out[1 + b] = (pm == yarg) ? 1.f : 0.f;
    }
}

__global__ void loss_sum(const float* __restrict__ lossp, float* __restrict__ out) {
    if (threadIdx.x == 0) {
        float sacc = 0.f;
        for (int b2 = 0; b2 < BIG; ++b2) sacc += lossp[b2];
        out[0] = sacc;
    }
}

extern "C" void kernel_launch(void* const* d_in, const int* in_sizes, int n_in,
                              void* d_out, int out_size, void* d_ws, size_t ws_size,
                              hipStream_t stream) {
    const int*   sentence = (const int*)d_in[0];
    const int*   pos1     = (const int*)d_in[1];
    const int*   pos2     = (const int*)d_in[2];
    const int*   tshape   = (const int*)d_in[3];
    const float* y_batch  = (const float*)d_in[4];
    const float* word_emb = (const float*)d_in[5];
    const float* p1e      = (const float*)d_in[6];
    const float* p2e      = (const float*)d_in[7];
    const float* w_ih_f   = (const float*)d_in[8];
    const float* w_hh_f   = (const float*)d_in[9];
    const float* b_ih_f   = (const float*)d_in[10];
    const float* b_hh_f   = (const float*)d_in[11];
    const float* w_ih_b   = (const float*)d_in[12];
    const float* w_hh_b   = (const float*)d_in[13];
    const float* b_ih_b   = (const float*)d_in[14];
    const float* b_hh_b   = (const float*)d_in[15];
    const float* att_w    = (const float*)d_in[16];
    const float* sen_a    = (const float*)d_in[17];
    const float* sen_r    = (const float*)d_in[18];
    const float* rel      = (const float*)d_in[19];
    const float* sen_d    = (const float*)d_in[20];
    float* out = (float*)d_out;

    // ws layout: tupF f16 | tupB f16 | senr f32 (wf aliased on top) | e | lossp
    const size_t TUP_E  = (size_t)NSENT * TT * HH;
    const size_t SENR_F = (size_t)NSENT * HH;
    _Float16* tupF = (_Float16*)d_ws;
    _Float16* tupB = tupF + TUP_E;
    float* senr  = (float*)(tupB + TUP_E);
    float* e     = senr + SENR_F;
    float* lossp = e + NSENT;
    uint4* wf    = (uint4*)senr;   // 1.18 MB inside senr's 3.77 MB; dead before attn writes senr

    prep_wfrag<<<288, 256, 0, stream>>>(w_ih_f, w_hh_f, w_ih_b, w_hh_b, wf);
    gru_kernel<<<(NSENT / GBLK) * 2, GTHR, GBLK * (256 + 128) * 4, stream>>>(
        sentence, pos1, pos2, wf, word_emb, p1e, p2e,
        b_ih_f, b_hh_f, b_ih_b, b_hh_b, tupF, tupB);
    attn_kernel<<<NSENT, ATHR, 0, stream>>>(tupF, tupB, att_w, sen_a, sen_r, senr, e);
    bag_kernel<<<BIG, 256, 0, stream>>>(tshape, e, senr, rel, sen_d, y_batch, out, lossp);
    loss_sum<<<1, 64, 0, stream>>>(lossp, out);
}